// Round 3
// baseline (134.216 us; speedup 1.0000x reference)
//
#include <hip/hip_runtime.h>

// Problem constants (from reference setup_inputs): h_all [T,B,D] fp32
#define T_DIM 2048
#define B_DIM 64
#define D_DIM 512
#define CHUNKS 32                         // t-chunks per batch
#define ROWS_PER_BLOCK (T_DIM / CHUNKS)   // 64 rows of h per block
#define NWAVES 4                          // 256 threads
#define ROWS_PER_WAVE (ROWS_PER_BLOCK / NWAVES)  // 16
#define RSQRT_D 0.044194173824159216f     // 1/sqrt(512)

// ws layout (floats): Ppart[CHUNKS][B][D] | Spart[CHUNKS][B] | counters[B] (uint)
#define PPART_FLOATS ((size_t)CHUNKS * B_DIM * D_DIM)          // 1,048,576
#define SPART_FLOATS ((size_t)CHUNKS * B_DIM)                  // 2,048
#define CNT_FLOAT_OFF (PPART_FLOATS + SPART_FLOATS)
#define CNT_BYTE_OFF  (CNT_FLOAT_OFF * 4)

// Single fused kernel: per (b, t-chunk) block computes its partial with one
// read of each h row, publishes it (release fence + device-scope atomic
// counter); the 32nd arriver per b acquire-fences and does the final
// reduce+divide for that b (fixed order c=0..31 -> deterministic), writing
// d_out directly. No second dispatch; finish overlaps the streaming tail.
__global__ __launch_bounds__(256)
void ap_fused_kernel(const float* __restrict__ h,
                     float* __restrict__ Ppart,     // [CHUNKS][B][D]
                     float* __restrict__ Spart,     // [CHUNKS][B]
                     unsigned* __restrict__ cnt,    // [B], zeroed each call
                     float* __restrict__ out)       // [B][D]
{
    const int b     = blockIdx.x % B_DIM;
    const int chunk = blockIdx.x / B_DIM;
    const int tid   = threadIdx.x;
    const int wave  = tid >> 6;
    const int lane  = tid & 63;

    const size_t rowStride = (size_t)B_DIM * D_DIM;   // floats between t's

    // h_last[b] fragment for this lane: d = lane*8 .. lane*8+7 (registers)
    const float* hl = h + (size_t)(T_DIM - 1) * rowStride + (size_t)b * D_DIM + lane * 8;
    const float4 hl0 = ((const float4*)hl)[0];
    const float4 hl1 = ((const float4*)hl)[1];

    float acc0 = 0.f, acc1 = 0.f, acc2 = 0.f, acc3 = 0.f;
    float acc4 = 0.f, acc5 = 0.f, acc6 = 0.f, acc7 = 0.f;
    float s = 0.f;

    const int t0 = chunk * ROWS_PER_BLOCK + wave * ROWS_PER_WAVE;
    const float* base = h + (size_t)t0 * rowStride + (size_t)b * D_DIM + lane * 8;

    #pragma unroll 4
    for (int i = 0; i < ROWS_PER_WAVE; ++i) {
        const float* p = base + (size_t)i * rowStride;
        const float4 v0 = ((const float4*)p)[0];
        const float4 v1 = ((const float4*)p)[1];

        // per-lane partial dot over its 8 elements
        float dp;
        dp = v0.x * hl0.x;
        dp = fmaf(v0.y, hl0.y, dp);
        dp = fmaf(v0.z, hl0.z, dp);
        dp = fmaf(v0.w, hl0.w, dp);
        dp = fmaf(v1.x, hl1.x, dp);
        dp = fmaf(v1.y, hl1.y, dp);
        dp = fmaf(v1.z, hl1.z, dp);
        dp = fmaf(v1.w, hl1.w, dp);

        // 64-lane butterfly reduce (wave = 64 on CDNA)
        #pragma unroll
        for (int m = 1; m < 64; m <<= 1)
            dp += __shfl_xor(dp, m, 64);

        const float r = fmaxf(dp * RSQRT_D, 0.f);

        acc0 = fmaf(r, v0.x, acc0);
        acc1 = fmaf(r, v0.y, acc1);
        acc2 = fmaf(r, v0.z, acc2);
        acc3 = fmaf(r, v0.w, acc3);
        acc4 = fmaf(r, v1.x, acc4);
        acc5 = fmaf(r, v1.y, acc5);
        acc6 = fmaf(r, v1.z, acc6);
        acc7 = fmaf(r, v1.w, acc7);
        s += r;   // r is wave-uniform after reduce
    }

    // Cross-wave reduce in LDS, then plain stores of this block's partial.
    __shared__ float accs[NWAVES][D_DIM];   // 8 KiB
    __shared__ float ssum[NWAVES];
    __shared__ unsigned old_sh;

    float4* dstA = (float4*)&accs[wave][lane * 8];
    dstA[0] = make_float4(acc0, acc1, acc2, acc3);
    dstA[1] = make_float4(acc4, acc5, acc6, acc7);
    if (lane == 0) ssum[wave] = s;
    __syncthreads();

    const size_t pbase = ((size_t)chunk * B_DIM + b) * D_DIM;
    #pragma unroll
    for (int k = 0; k < 2; ++k) {
        const int d = tid + k * 256;
        Ppart[pbase + d] = accs[0][d] + accs[1][d] + accs[2][d] + accs[3][d];
    }
    if (tid == 0) {
        Spart[chunk * B_DIM + b] = ssum[0] + ssum[1] + ssum[2] + ssum[3];
    }

    // Publish: make this block's stores device-visible, then count arrival.
    __syncthreads();                 // compiler drains vmcnt before barrier
    if (tid == 0) {
        __threadfence();             // release: write back L2 (cross-XCD vis)
        old_sh = atomicAdd(&cnt[b], 1u);
    }
    __syncthreads();

    if (old_sh == CHUNKS - 1) {
        // Last arriver for this b: all 32 partials are device-visible.
        __threadfence();             // acquire: invalidate stale L1/L2 lines

        float sden = 0.f;
        #pragma unroll
        for (int c = 0; c < CHUNKS; ++c)
            sden += Spart[c * B_DIM + b];
        sden += 1e-9f;

        #pragma unroll
        for (int k = 0; k < 2; ++k) {
            const int d = tid + k * 256;
            float acc = 0.f;
            #pragma unroll
            for (int c = 0; c < CHUNKS; ++c)
                acc += Ppart[((size_t)c * B_DIM + b) * D_DIM + d];
            out[(size_t)b * D_DIM + d] = acc / sden;
        }
    }
}

extern "C" void kernel_launch(void* const* d_in, const int* in_sizes, int n_in,
                              void* d_out, int out_size, void* d_ws, size_t ws_size,
                              hipStream_t stream)
{
    const float* h = (const float*)d_in[0];   // h_all [T,B,D] fp32; xin (d_in[1]) unused
    float* ws    = (float*)d_ws;
    float* Ppart = ws;                                   // [CHUNKS][B][D]
    float* Spart = ws + PPART_FLOATS;                    // [CHUNKS][B]
    unsigned* cnt = (unsigned*)((char*)d_ws + CNT_BYTE_OFF); // [B]

    // Counters must be zero at kernel start EVERY call (ws poisoned once to
    // 0xAA, never re-poisoned). 256-byte graph memset node ~1 us.
    hipMemsetAsync(cnt, 0, B_DIM * sizeof(unsigned), stream);

    ap_fused_kernel<<<B_DIM * CHUNKS, 256, 0, stream>>>(h, Ppart, Spart, cnt, (float*)d_out);
}

// Round 4
// 51.212 us; speedup vs baseline: 2.6208x; 2.6208x over previous
//
#include <hip/hip_runtime.h>

// Problem constants (from reference setup_inputs): h_all [T,B,D] fp32
#define T_DIM 2048
#define B_DIM 64
#define D_DIM 512
#define CHUNKS 32                         // t-chunks per batch
#define ROWS_PER_BLOCK (T_DIM / CHUNKS)   // 64 rows of h per block
#define NWAVES 4                          // 256 threads
#define ROWS_PER_WAVE (ROWS_PER_BLOCK / NWAVES)  // 16
#define RSQRT_D 0.044194173824159216f     // 1/sqrt(512)

// ws layout (floats): Ppart[B][CHUNKS][D] | Spart[B][CHUNKS]
// [b][c][d] layout => pass 2 reads one contiguous 64 KiB stream per b.

// Pass 1: per (b, t-chunk) block, compute partial numerator Ppart[b][chunk][:]
// and partial denominator Spart[b][chunk] with a single read of each h row.
// Plain stores, no atomics, no device fences (Round-3 lesson: 2048 blocks x
// __threadfence => 2048 serialized L2 writeback-drains, +150 us).
// Workspace fully overwritten each call -> no memset, bit-deterministic.
__global__ __launch_bounds__(256)
void ap_partial_kernel(const float* __restrict__ h,
                       float* __restrict__ Ppart,   // [B][CHUNKS][D]
                       float* __restrict__ Spart)   // [B][CHUNKS]
{
    const int b     = blockIdx.x % B_DIM;
    const int chunk = blockIdx.x / B_DIM;
    const int tid   = threadIdx.x;
    const int wave  = tid >> 6;
    const int lane  = tid & 63;

    const size_t rowStride = (size_t)B_DIM * D_DIM;   // floats between t's

    // h_last[b] fragment for this lane: d = lane*8 .. lane*8+7 (registers)
    const float* hl = h + (size_t)(T_DIM - 1) * rowStride + (size_t)b * D_DIM + lane * 8;
    const float4 hl0 = ((const float4*)hl)[0];
    const float4 hl1 = ((const float4*)hl)[1];

    float acc0 = 0.f, acc1 = 0.f, acc2 = 0.f, acc3 = 0.f;
    float acc4 = 0.f, acc5 = 0.f, acc6 = 0.f, acc7 = 0.f;
    float s = 0.f;

    const int t0 = chunk * ROWS_PER_BLOCK + wave * ROWS_PER_WAVE;
    const float* base = h + (size_t)t0 * rowStride + (size_t)b * D_DIM + lane * 8;

    #pragma unroll 4
    for (int i = 0; i < ROWS_PER_WAVE; ++i) {
        const float* p = base + (size_t)i * rowStride;
        const float4 v0 = ((const float4*)p)[0];
        const float4 v1 = ((const float4*)p)[1];

        // per-lane partial dot over its 8 elements
        float dp;
        dp = v0.x * hl0.x;
        dp = fmaf(v0.y, hl0.y, dp);
        dp = fmaf(v0.z, hl0.z, dp);
        dp = fmaf(v0.w, hl0.w, dp);
        dp = fmaf(v1.x, hl1.x, dp);
        dp = fmaf(v1.y, hl1.y, dp);
        dp = fmaf(v1.z, hl1.z, dp);
        dp = fmaf(v1.w, hl1.w, dp);

        // 64-lane butterfly reduce (wave = 64 on CDNA)
        #pragma unroll
        for (int m = 1; m < 64; m <<= 1)
            dp += __shfl_xor(dp, m, 64);

        const float r = fmaxf(dp * RSQRT_D, 0.f);

        acc0 = fmaf(r, v0.x, acc0);
        acc1 = fmaf(r, v0.y, acc1);
        acc2 = fmaf(r, v0.z, acc2);
        acc3 = fmaf(r, v0.w, acc3);
        acc4 = fmaf(r, v1.x, acc4);
        acc5 = fmaf(r, v1.y, acc5);
        acc6 = fmaf(r, v1.z, acc6);
        acc7 = fmaf(r, v1.w, acc7);
        s += r;   // r is wave-uniform after reduce
    }

    // Cross-wave reduce in LDS, then plain stores of this block's partial.
    __shared__ float accs[NWAVES][D_DIM];   // 8 KiB
    __shared__ float ssum[NWAVES];

    float4* dstA = (float4*)&accs[wave][lane * 8];
    dstA[0] = make_float4(acc0, acc1, acc2, acc3);
    dstA[1] = make_float4(acc4, acc5, acc6, acc7);
    if (lane == 0) ssum[wave] = s;
    __syncthreads();

    const size_t pbase = ((size_t)b * CHUNKS + chunk) * D_DIM;
    #pragma unroll
    for (int k = 0; k < 2; ++k) {
        const int d = tid + k * 256;
        Ppart[pbase + d] = accs[0][d] + accs[1][d] + accs[2][d] + accs[3][d];
    }
    if (tid == 0) {
        Spart[b * CHUNKS + chunk] = ssum[0] + ssum[1] + ssum[2] + ssum[3];
    }
}

// Pass 2: out[b,d] = sum_c P[b][c][d] / (sum_c S[b][c] + 1e-9)
// 64 blocks x 128 threads; thread t owns d=4t (float4). Per-b reads are one
// contiguous 64 KiB stream, mostly L2/L3-hot. Fixed order -> deterministic.
__global__ __launch_bounds__(128)
void ap_reduce_kernel(const float* __restrict__ Ppart,
                      const float* __restrict__ Spart,
                      float* __restrict__ out)
{
    const int b = blockIdx.x;
    const int t = threadIdx.x;

    // Denominator: block-uniform addresses -> scalar loads from one 128B line.
    float s = 0.f;
    #pragma unroll
    for (int c = 0; c < CHUNKS; ++c)
        s += Spart[b * CHUNKS + c];
    const float inv = 1.0f / (s + 1e-9f);

    const float4* P = (const float4*)(Ppart + (size_t)b * CHUNKS * D_DIM);
    const int nd4 = D_DIM / 4;   // 128 float4 per chunk row

    float4 acc = make_float4(0.f, 0.f, 0.f, 0.f);
    #pragma unroll
    for (int c = 0; c < CHUNKS; ++c) {
        const float4 v = P[c * nd4 + t];
        acc.x += v.x; acc.y += v.y; acc.z += v.z; acc.w += v.w;
    }
    acc.x *= inv; acc.y *= inv; acc.z *= inv; acc.w *= inv;
    ((float4*)(out + (size_t)b * D_DIM))[t] = acc;
}

extern "C" void kernel_launch(void* const* d_in, const int* in_sizes, int n_in,
                              void* d_out, int out_size, void* d_ws, size_t ws_size,
                              hipStream_t stream)
{
    const float* h = (const float*)d_in[0];   // h_all [T,B,D] fp32; xin (d_in[1]) unused
    float* ws    = (float*)d_ws;
    float* Ppart = ws;                                      // [B][CHUNKS][D]
    float* Spart = ws + (size_t)B_DIM * CHUNKS * D_DIM;     // [B][CHUNKS]

    ap_partial_kernel<<<B_DIM * CHUNKS, 256, 0, stream>>>(h, Ppart, Spart);
    ap_reduce_kernel<<<B_DIM, 128, 0, stream>>>(Ppart, Spart, (float*)d_out);
}